// Round 1
// 152.980 us; speedup vs baseline: 1.2585x; 1.2585x over previous
//
#include <hip/hip_runtime.h>
#include <math.h>

#define NSTEPS 216
#define SEG 54                 // steps per segment (= per thread)
#define NSEG 4                 // segments (waves) per row
#define ROWS 64                // rows per block (= lanes per wave)
#define THREADS (ROWS * NSEG)  // 256
#define CSTR 55                // LDS staging stride, coprime with 32 banks

// Batch-independent per-step tables, recomputed every call (graph-safe).
__device__ float g_th[NSTEPS];    // atan2 trajectory
__device__ float g_hz0[NSTEPS];   // H * z0_t

__global__ void traj_kernel() {
    __shared__ float xs[NSTEPS], ys[NSTEPS];
    const int t = threadIdx.x;
    if (t == 0) {
        // Serial part: only the cheap x/y recurrence (sqrt + FMAs).
        float x = (float)(-0.417750770388669);
        float y = (float)(-0.9085616622823985);
        const float W = (float)(2.0 * M_PI);
        const float H = (float)(1.0 / 216.0);
        for (int n = 0; n < NSTEPS; ++n) {
            xs[n] = x;                      // th uses pre-update x,y
            ys[n] = y;
            float alpha = 1.0f - sqrtf(x * x + y * y);
            float fx = alpha * x - W * y;
            float fy = alpha * y + W * x;
            x = x + H * fx;
            y = y + H * fy;
        }
    }
    __syncthreads();
    if (t < NSTEPS) {
        g_th[t] = atan2f(ys[t], xs[t]);     // 216 atan2s in parallel
        float tf = (float)t / 216.0f;
        g_hz0[t] = (float)(1.0 / 216.0) * (0.005f * sinf(1.5707964f * tf));
    }
}

// z_n = K*z_{n-1} + c_t is AFFINE in z with z-independent forcing c_t.
// => time-parallel: 4 threads/row each own 54 steps, compute c_t ONCE
// (cached in 54 VGPRs), combine segment affine maps (z -> K^54 z + S),
// then replay with cheap FMAs. Kills the old pass-2 recompute and lifts
// the grid from 2048 to 8192 waves (8 -> ~16-20 waves/CU).
__global__ __launch_bounds__(THREADS, 4) void euler_kernel(const float* __restrict__ prm,
                                                           const float* __restrict__ v0,
                                                           float* __restrict__ out) {
    __shared__ float th_s[NSTEPS];
    __shared__ float hz0_s[NSTEPS];
    __shared__ float Sz[NSEG][ROWS];      // segment offsets S
    __shared__ float Smn[NSEG][ROWS];     // per-segment min
    __shared__ float Smx[NSEG][ROWS];     // per-segment max
    __shared__ float st_s[ROWS * CSTR];   // 64 rows x 54 scaled outputs, stride 55

    const int tid = threadIdx.x;
    const int row = tid & (ROWS - 1);     // lane within wave
    const int seg = tid >> 6;             // wave id = segment id

    for (int i = tid; i < NSTEPS; i += THREADS) {
        th_s[i] = g_th[i];
        hz0_s[i] = g_hz0[i];
    }

    const int b = blockIdx.x * ROWS + row;
    const float* p = prm + (size_t)b * 15;

    // gaussian_j(d) = a*d*exp(-d^2/(2b^2)) = d * exp(d^2*c + ln a)
    float tj[5], cj[5], la[5];
#pragma unroll
    for (int j = 0; j < 5; ++j) {
        float a  = p[3 * j + 0];
        float bb = p[3 * j + 1];
        tj[j] = p[3 * j + 2];
        cj[j] = -1.0f / (2.0f * bb * bb);
        la[j] = __logf(a);
    }

    const float zinit = v0[b];
    const float H = (float)(1.0 / 216.0);
    const float K = 1.0f - H;
    // A = K^54 by squaring (uniform, 6 muls)
    const float K2 = K * K, K4 = K2 * K2, K8 = K4 * K4;
    const float K16 = K8 * K8, K32 = K16 * K16;
    const float A = K32 * K16 * K4 * K2;   // 32+16+4+2 = 54

    __syncthreads();

    // ---- heavy pass (ONCE): forcing terms c_t for my 54 steps ----
    const int t0 = seg * SEG;
    float c[SEG];
    float S = 0.0f;                        // segment applied to z=0
#pragma unroll
    for (int i = 0; i < SEG; ++i) {
        float th = th_s[t0 + i];
        float G = 0.0f;
#pragma unroll
        for (int j = 0; j < 5; ++j) {
            float d = th - tj[j];
            G = fmaf(d, __expf(fmaf(d * d, cj[j], la[j])), G);
        }
        float ci = fmaf(-H, G, hz0_s[t0 + i]);
        c[i] = ci;
        S = fmaf(S, K, ci);
    }
    Sz[seg][row] = S;
    __syncthreads();

    // ---- combine: z at my segment start (wave-uniform trip count) ----
    float z = zinit;
#pragma unroll
    for (int j = 0; j < NSEG - 1; ++j)
        if (j < seg) z = fmaf(z, A, Sz[j][row]);

    // ---- replay: cheap FMAs, overwrite c[] with z_t, track min/max ----
    float zmn = 3.4e38f, zmx = -3.4e38f;
#pragma unroll
    for (int i = 0; i < SEG; ++i) {
        z = fmaf(z, K, c[i]);
        c[i] = z;
        zmn = fminf(zmn, z);
        zmx = fmaxf(zmx, z);
    }
    Smn[seg][row] = zmn;
    Smx[seg][row] = zmx;
    __syncthreads();
#pragma unroll
    for (int j = 0; j < NSEG; ++j) {
        zmn = fminf(zmn, Smn[j][row]);
        zmx = fmaxf(zmx, Smx[j][row]);
    }
    const float s = 0.042557f / (zmx - zmn);
    const float o = fmaf(-zmn, s, -0.01563f);

    // ---- staged coalesced write, one chunk per segment ----
    float* outB = out + (size_t)blockIdx.x * (ROWS * NSTEPS);
#pragma unroll
    for (int ch = 0; ch < NSEG; ++ch) {
        if (seg == ch) {
#pragma unroll
            for (int i = 0; i < SEG; ++i)
                st_s[row * CSTR + i] = fmaf(c[i], s, o);
        }
        __syncthreads();
        // 64*54 = 3456 staged elements -> 256 threads x 13.5
#pragma unroll
        for (int k = 0; k < 13; ++k) {
            unsigned idx = (unsigned)tid + THREADS * k;
            unsigned r = idx / 54u;
            unsigned tt = idx - r * 54u;
            outB[r * NSTEPS + ch * SEG + tt] = st_s[r * CSTR + tt];
        }
        if (tid < 128) {
            unsigned idx = (unsigned)tid + THREADS * 13;
            unsigned r = idx / 54u;
            unsigned tt = idx - r * 54u;
            outB[r * NSTEPS + ch * SEG + tt] = st_s[r * CSTR + tt];
        }
        __syncthreads();
    }
}

extern "C" void kernel_launch(void* const* d_in, const int* in_sizes, int n_in,
                              void* d_out, int out_size, void* d_ws, size_t ws_size,
                              hipStream_t stream) {
    const float* x  = (const float*)d_in[0];
    const float* v0 = (const float*)d_in[1];
    float* out = (float*)d_out;
    const int nb = in_sizes[1];              // 131072 batch rows

    hipLaunchKernelGGL(traj_kernel, dim3(1), dim3(256), 0, stream);
    hipLaunchKernelGGL(euler_kernel, dim3(nb / ROWS), dim3(THREADS), 0, stream, x, v0, out);
}

// Round 2
// 150.591 us; speedup vs baseline: 1.2784x; 1.0159x over previous
//
#include <hip/hip_runtime.h>
#include <math.h>

#define NSTEPS 216
#define SEG 27                 // steps per segment (= per thread)
#define NSEG 8                 // segments (waves) per row
#define ROWS 64                // rows per block (= lanes per wave)
#define THREADS (ROWS * NSEG)  // 512
#define CSTR 55                // LDS staging stride, coprime with 32 banks

#if __has_builtin(__builtin_amdgcn_exp2f)
#define EXP2F(x) __builtin_amdgcn_exp2f(x)
#else
#define EXP2F(x) exp2f(x)
#endif

// Batch-independent per-step tables, recomputed every call (graph-safe).
__device__ float g_th[NSTEPS];    // atan2 trajectory
__device__ float g_hz0[NSTEPS];   // H * z0_t

__global__ void traj_kernel() {
    __shared__ float xs[NSTEPS], ys[NSTEPS];
    const int t = threadIdx.x;
    if (t == 0) {
        // Serial part: only the cheap x/y recurrence (sqrt + FMAs).
        float x = (float)(-0.417750770388669);
        float y = (float)(-0.9085616622823985);
        const float W = (float)(2.0 * M_PI);
        const float H = (float)(1.0 / 216.0);
        for (int n = 0; n < NSTEPS; ++n) {
            xs[n] = x;                      // th uses pre-update x,y
            ys[n] = y;
            float alpha = 1.0f - sqrtf(x * x + y * y);
            float fx = alpha * x - W * y;
            float fy = alpha * y + W * x;
            x = x + H * fx;
            y = y + H * fy;
        }
    }
    __syncthreads();
    if (t < NSTEPS) {
        g_th[t] = atan2f(ys[t], xs[t]);     // 216 atan2s in parallel
        float tf = (float)t / 216.0f;
        g_hz0[t] = (float)(1.0 / 216.0) * (0.005f * sinf(1.5707964f * tf));
    }
}

// z_n = K*z_{n-1} + c_t is AFFINE in z with z-independent forcing c_t.
// => time-parallel: 8 threads/row each own 27 steps, compute c_t ONCE
// (cached in 27 VGPRs), combine segment affine maps (z -> K^27 z + S),
// then replay with cheap FMAs.
// SEG=27 (vs 54) + exp2-folded constants: targets <=64 VGPR so the
// forced __launch_bounds__(512,8) gives 8 waves/SIMD to hide the
// quarter-rate v_exp_f32 latency.
__global__ __launch_bounds__(THREADS, 8) void euler_kernel(const float* __restrict__ prm,
                                                           const float* __restrict__ v0,
                                                           float* __restrict__ out) {
    __shared__ float th_s[NSTEPS];
    __shared__ float hz0_s[NSTEPS];
    __shared__ float Sz[NSEG][ROWS];      // segment offsets S
    __shared__ float Smn[NSEG][ROWS];     // per-segment min
    __shared__ float Smx[NSEG][ROWS];     // per-segment max
    __shared__ float st_s[ROWS * CSTR];   // 64 rows x 54 scaled outputs, stride 55

    const int tid = threadIdx.x;
    const int row = tid & (ROWS - 1);     // lane within wave
    const int seg = tid >> 6;             // wave id = segment id (wave-uniform)

    if (tid < NSTEPS) {
        th_s[tid] = g_th[tid];
        hz0_s[tid] = g_hz0[tid];
    }

    const int b = blockIdx.x * ROWS + row;
    const float* p = prm + (size_t)b * 15;

    // gaussian_j(d) = a*d*exp(-d^2/(2b^2)) = d * exp2(d^2*cj2 + la2)
    // with log2e folded into cj2/la2 so the hot loop is pure v_exp_f32.
    const float LOG2E = 1.4426950408889634f;
    float tj[5], cj2[5], la2[5];
#pragma unroll
    for (int j = 0; j < 5; ++j) {
        float a  = p[3 * j + 0];
        float bb = p[3 * j + 1];
        tj[j] = p[3 * j + 2];
        cj2[j] = -LOG2E / (2.0f * bb * bb);
        la2[j] = __log2f(a);
    }

    const float zinit = v0[b];
    const float H = (float)(1.0 / 216.0);
    const float K = 1.0f - H;
    // A = K^27 by squaring (uniform): 16+8+2+1
    const float K2 = K * K, K8 = K2 * K2 * K2 * K2;
    const float A = K8 * K8 * K8 * K2 * K;

    __syncthreads();

    // ---- heavy pass (ONCE): forcing terms c_t for my 27 steps ----
    const int t0 = seg * SEG;
    float c[SEG];
    float S = 0.0f;                        // segment map applied to z=0
#pragma unroll
    for (int i = 0; i < SEG; ++i) {
        float th = th_s[t0 + i];
        float G = 0.0f;
#pragma unroll
        for (int j = 0; j < 5; ++j) {
            float d = th - tj[j];
            G = fmaf(d, EXP2F(fmaf(d * d, cj2[j], la2[j])), G);
        }
        float ci = fmaf(-H, G, hz0_s[t0 + i]);
        c[i] = ci;
        S = fmaf(S, K, ci);
    }
    Sz[seg][row] = S;
    __syncthreads();

    // ---- combine: z at my segment start (seg is wave-uniform -> no div) ----
    float z = zinit;
#pragma unroll
    for (int j = 0; j < NSEG - 1; ++j)
        if (j < seg) z = fmaf(z, A, Sz[j][row]);

    // ---- replay: cheap FMAs, overwrite c[] with z_t, track min/max ----
    float zmn = 3.4e38f, zmx = -3.4e38f;
#pragma unroll
    for (int i = 0; i < SEG; ++i) {
        z = fmaf(z, K, c[i]);
        c[i] = z;
        zmn = fminf(zmn, z);
        zmx = fmaxf(zmx, z);
    }
    Smn[seg][row] = zmn;
    Smx[seg][row] = zmx;
    __syncthreads();
#pragma unroll
    for (int j = 0; j < NSEG; ++j) {
        zmn = fminf(zmn, Smn[j][row]);
        zmx = fmaxf(zmx, Smx[j][row]);
    }
    const float s = 0.042557f / (zmx - zmn);
    const float o = fmaf(-zmn, s, -0.01563f);

    // ---- staged coalesced write: chunk = 2 segments = 54 steps ----
    float* outB = out + (size_t)blockIdx.x * (ROWS * NSTEPS);
#pragma unroll
    for (int ch = 0; ch < NSEG / 2; ++ch) {
        if ((seg >> 1) == ch) {            // wave-uniform
            const int base = (seg & 1) * SEG;
#pragma unroll
            for (int i = 0; i < SEG; ++i)
                st_s[row * CSTR + base + i] = fmaf(c[i], s, o);
        }
        __syncthreads();
        // 64*54 = 3456 staged elements -> 512 threads x 6.75
#pragma unroll
        for (int k = 0; k < 6; ++k) {
            unsigned idx = (unsigned)tid + THREADS * k;
            unsigned r = idx / 54u;
            unsigned tt = idx - r * 54u;
            outB[r * NSTEPS + ch * 54 + tt] = st_s[r * CSTR + tt];
        }
        if (tid < 3456 - 6 * THREADS) {
            unsigned idx = (unsigned)tid + THREADS * 6;
            unsigned r = idx / 54u;
            unsigned tt = idx - r * 54u;
            outB[r * NSTEPS + ch * 54 + tt] = st_s[r * CSTR + tt];
        }
        __syncthreads();
    }
}

extern "C" void kernel_launch(void* const* d_in, const int* in_sizes, int n_in,
                              void* d_out, int out_size, void* d_ws, size_t ws_size,
                              hipStream_t stream) {
    const float* x  = (const float*)d_in[0];
    const float* v0 = (const float*)d_in[1];
    float* out = (float*)d_out;
    const int nb = in_sizes[1];              // 131072 batch rows

    hipLaunchKernelGGL(traj_kernel, dim3(1), dim3(256), 0, stream);
    hipLaunchKernelGGL(euler_kernel, dim3(nb / ROWS), dim3(THREADS), 0, stream, x, v0, out);
}

// Round 4
// 150.437 us; speedup vs baseline: 1.2797x; 1.0010x over previous
//
#include <hip/hip_runtime.h>
#include <math.h>

#define NSTEPS 216
#define SEG 27                 // steps per segment (= per thread)
#define CREG 18                // c[0..CREG) in VGPRs, rest in LDS
#define NSEG 8                 // segments (waves) per row
#define ROWS 64                // rows per block (= lanes per wave)
#define THREADS (ROWS * NSEG)  // 512
#define CSTR 55                // LDS staging stride, coprime with 32 banks

#if __has_builtin(__builtin_amdgcn_exp2f)
#define EXP2F(x) __builtin_amdgcn_exp2f(x)
#else
#define EXP2F(x) exp2f(x)
#endif

// Batch-independent per-step tables, recomputed every call (graph-safe).
__device__ float g_th[NSTEPS];    // atan2 trajectory
__device__ float g_hz0[NSTEPS];   // H * z0_t

__global__ void traj_kernel() {
    __shared__ float xs[NSTEPS], ys[NSTEPS];
    const int t = threadIdx.x;
    if (t == 0) {
        // Serial part: only the cheap x/y recurrence (sqrt + FMAs).
        float x = (float)(-0.417750770388669);
        float y = (float)(-0.9085616622823985);
        const float W = (float)(2.0 * M_PI);
        const float H = (float)(1.0 / 216.0);
        for (int n = 0; n < NSTEPS; ++n) {
            xs[n] = x;                      // th uses pre-update x,y
            ys[n] = y;
            float alpha = 1.0f - sqrtf(x * x + y * y);
            float fx = alpha * x - W * y;
            float fy = alpha * y + W * x;
            x = x + H * fx;
            y = y + H * fy;
        }
    }
    __syncthreads();
    if (t < NSTEPS) {
        g_th[t] = atan2f(ys[t], xs[t]);     // 216 atan2s in parallel
        float tf = (float)t / 216.0f;
        g_hz0[t] = (float)(1.0 / 216.0) * (0.005f * sinf(1.5707964f * tf));
    }
}

// z_n = K*z_{n-1} + c_t is AFFINE in z with z-independent forcing c_t.
// => time-parallel: 8 threads/row each own 27 steps, compute c_t ONCE,
// combine segment affine maps (z -> K^27 z + S), then replay with cheap
// FMAs. R3/R4: c[] split 18-in-VGPR + 9-in-LDS so the forced
// __launch_bounds__(512,8) (<=64 VGPR) is met WITHOUT scratch spills
// (R2's null result attributed to spilling at the 64-reg cliff).
// R4 = R3 resubmitted verbatim; R3 failed on container infra, no data.
__global__ __launch_bounds__(THREADS, 8) void euler_kernel(const float* __restrict__ prm,
                                                           const float* __restrict__ v0,
                                                           float* __restrict__ out) {
    __shared__ float th_s[NSTEPS];
    __shared__ float hz0_s[NSTEPS];
    __shared__ float Sz[NSEG][ROWS];      // segment offsets S
    __shared__ float Smn[NSEG][ROWS];     // per-segment min
    __shared__ float Smx[NSEG][ROWS];     // per-segment max
    __shared__ float st_s[ROWS * CSTR];   // 64 rows x 54 scaled outputs, stride 55
    __shared__ float c_lds[SEG - CREG][THREADS];  // 9 x 512, lane-stride: conflict-free

    const int tid = threadIdx.x;
    const int row = tid & (ROWS - 1);     // lane within wave
    const int seg = tid >> 6;             // wave id = segment id (wave-uniform)

    if (tid < NSTEPS) {
        th_s[tid] = g_th[tid];
        hz0_s[tid] = g_hz0[tid];
    }

    const int b = blockIdx.x * ROWS + row;
    const float* p = prm + (size_t)b * 15;

    // gaussian_j(d) = a*d*exp(-d^2/(2b^2)) = d * exp2(d^2*cj2 + la2)
    // with log2e folded into cj2/la2 so the hot loop is pure v_exp_f32.
    const float LOG2E = 1.4426950408889634f;
    float tj[5], cj2[5], la2[5];
#pragma unroll
    for (int j = 0; j < 5; ++j) {
        float a  = p[3 * j + 0];
        float bb = p[3 * j + 1];
        tj[j] = p[3 * j + 2];
        cj2[j] = -LOG2E / (2.0f * bb * bb);
        la2[j] = __log2f(a);
    }

    const float zinit = v0[b];
    const float H = (float)(1.0 / 216.0);
    const float K = 1.0f - H;
    // A = K^27 by squaring (uniform): 16+8+2+1
    const float K2 = K * K, K8 = K2 * K2 * K2 * K2;
    const float A = K8 * K8 * K8 * K2 * K;

    __syncthreads();

    // ---- heavy pass (ONCE): forcing terms c_t for my 27 steps ----
    const int t0 = seg * SEG;
    float c[CREG];
    float S = 0.0f;                        // segment map applied to z=0
#pragma unroll
    for (int i = 0; i < SEG; ++i) {
        float th = th_s[t0 + i];
        float G = 0.0f;
#pragma unroll
        for (int j = 0; j < 5; ++j) {
            float d = th - tj[j];
            G = fmaf(d, EXP2F(fmaf(d * d, cj2[j], la2[j])), G);
        }
        float ci = fmaf(-H, G, hz0_s[t0 + i]);
        if (i < CREG) c[i] = ci;           // compile-time split (full unroll)
        else          c_lds[i - CREG][tid] = ci;
        S = fmaf(S, K, ci);
    }
    Sz[seg][row] = S;
    __syncthreads();

    // ---- combine: z at my segment start (seg is wave-uniform -> no div) ----
    float z = zinit;
#pragma unroll
    for (int j = 0; j < NSEG - 1; ++j)
        if (j < seg) z = fmaf(z, A, Sz[j][row]);

    // ---- replay: cheap FMAs, overwrite storage with z_t, track min/max ----
    float zmn = 3.4e38f, zmx = -3.4e38f;
#pragma unroll
    for (int i = 0; i < SEG; ++i) {
        float ci = (i < CREG) ? c[i] : c_lds[i - CREG][tid];
        z = fmaf(z, K, ci);
        if (i < CREG) c[i] = z;
        else          c_lds[i - CREG][tid] = z;
        zmn = fminf(zmn, z);
        zmx = fmaxf(zmx, z);
    }
    Smn[seg][row] = zmn;
    Smx[seg][row] = zmx;
    __syncthreads();
#pragma unroll
    for (int j = 0; j < NSEG; ++j) {
        zmn = fminf(zmn, Smn[j][row]);
        zmx = fmaxf(zmx, Smx[j][row]);
    }
    const float s = 0.042557f / (zmx - zmn);
    const float o = fmaf(-zmn, s, -0.01563f);

    // ---- staged coalesced write: chunk = 2 segments = 54 steps ----
    float* outB = out + (size_t)blockIdx.x * (ROWS * NSTEPS);
#pragma unroll
    for (int ch = 0; ch < NSEG / 2; ++ch) {
        if ((seg >> 1) == ch) {            // wave-uniform
            const int base = (seg & 1) * SEG;
#pragma unroll
            for (int i = 0; i < SEG; ++i) {
                float zi = (i < CREG) ? c[i] : c_lds[i - CREG][tid];
                st_s[row * CSTR + base + i] = fmaf(zi, s, o);
            }
        }
        __syncthreads();
        // 64*54 = 3456 staged elements -> 512 threads x 6.75
#pragma unroll
        for (int k = 0; k < 6; ++k) {
            unsigned idx = (unsigned)tid + THREADS * k;
            unsigned r = idx / 54u;
            unsigned tt = idx - r * 54u;
            outB[r * NSTEPS + ch * 54 + tt] = st_s[r * CSTR + tt];
        }
        if (tid < 3456 - 6 * THREADS) {
            unsigned idx = (unsigned)tid + THREADS * 6;
            unsigned r = idx / 54u;
            unsigned tt = idx - r * 54u;
            outB[r * NSTEPS + ch * 54 + tt] = st_s[r * CSTR + tt];
        }
        __syncthreads();
    }
}

extern "C" void kernel_launch(void* const* d_in, const int* in_sizes, int n_in,
                              void* d_out, int out_size, void* d_ws, size_t ws_size,
                              hipStream_t stream) {
    const float* x  = (const float*)d_in[0];
    const float* v0 = (const float*)d_in[1];
    float* out = (float*)d_out;
    const int nb = in_sizes[1];              // 131072 batch rows

    hipLaunchKernelGGL(traj_kernel, dim3(1), dim3(256), 0, stream);
    hipLaunchKernelGGL(euler_kernel, dim3(nb / ROWS), dim3(THREADS), 0, stream, x, v0, out);
}